// Round 2
// baseline (396.610 us; speedup 1.0000x reference)
//
#include <hip/hip_runtime.h>

// PositionLinear + ReLU: out[t,:] = relu(W @ x[t,:] + b)
// x: [T=1048576][64] fp32, W: [64][64] fp32, b: [64] fp32, out: [T][64] fp32
// Memory-bound: 512 MiB min HBM traffic @ ~6.3 TB/s => ~85 us floor.
//
// Round-2 structure: one thread per token, 64 ACCUMULATORS register-resident
// (cannot be rematerialized, unlike round-1's x-row which the compiler sank
// into the loop and re-loaded 16x from L2). x streams through as float4
// chunks, each loaded exactly once. All 64 outputs stored at the end as 16
// consecutive dwordx4 -> each 64B line completed immediately (round 1 showed
// 2.3x write amplification from partially-written line evictions).
// W/bias accesses are wave-uniform -> scalar s_load path (SGPR operands to
// v_fmac_f32), keeping the VALU ~pure FMA.

#define N_DIM 64
#define TOKENS (32u * 32768u)  // B * P = 1,048,576

__global__ __launch_bounds__(256) void poslin_relu_kernel(
    const float* __restrict__ x,
    const float* __restrict__ W,
    const float* __restrict__ bias,
    float* __restrict__ out)
{
    const size_t t = (size_t)blockIdx.x * blockDim.x + threadIdx.x;
    if (t >= TOKENS) return;

    const float4* __restrict__ xr = reinterpret_cast<const float4*>(x + t * N_DIM);

    // 64 accumulators, init from bias (wave-uniform -> s_load).
    float acc[N_DIM];
#pragma unroll
    for (int o = 0; o < N_DIM; ++o) acc[o] = bias[o];

    // Stream x in 16 float4 chunks; each chunk feeds 256 FMAs (64 outputs x 4 k).
    // kc is a uniform loop counter and o is an unroll constant, so every W
    // index is wave-uniform -> scalar loads.
#pragma unroll 4
    for (int kc = 0; kc < 16; ++kc) {
        const float4 xv = xr[kc];
        const float* __restrict__ wk = W + 4 * kc;
#pragma unroll
        for (int o = 0; o < N_DIM; ++o) {
            const float* __restrict__ wr = wk + (size_t)o * N_DIM;
            float a = acc[o];
            a = fmaf(xv.x, wr[0], a);
            a = fmaf(xv.y, wr[1], a);
            a = fmaf(xv.z, wr[2], a);
            a = fmaf(xv.w, wr[3], a);
            acc[o] = a;
        }
    }

    // ReLU + store: 16 consecutive dwordx4 complete all 4 cache lines of the
    // row back-to-back -> full-line writeback, no partial-line eviction.
    float4* __restrict__ orow = reinterpret_cast<float4*>(out + t * N_DIM);
#pragma unroll
    for (int i = 0; i < 16; ++i) {
        float4 r;
        r.x = fmaxf(acc[4 * i + 0], 0.0f);
        r.y = fmaxf(acc[4 * i + 1], 0.0f);
        r.z = fmaxf(acc[4 * i + 2], 0.0f);
        r.w = fmaxf(acc[4 * i + 3], 0.0f);
        orow[i] = r;
    }
}

extern "C" void kernel_launch(void* const* d_in, const int* in_sizes, int n_in,
                              void* d_out, int out_size, void* d_ws, size_t ws_size,
                              hipStream_t stream) {
    const float* x    = (const float*)d_in[0];
    const float* W    = (const float*)d_in[1];
    const float* bias = (const float*)d_in[2];
    float* out        = (float*)d_out;

    const int block = 256;
    const int grid  = (int)((TOKENS + block - 1) / block);  // 4096 blocks
    poslin_relu_kernel<<<grid, block, 0, stream>>>(x, W, bias, out);
}

// Round 3
// 300.037 us; speedup vs baseline: 1.3219x; 1.3219x over previous
//
#include <hip/hip_runtime.h>

// PositionLinear + ReLU: out[t,:] = relu(W @ x[t,:] + b)
// x: [T=1048576][64] f32, W: [64][64] f32, b: [64] f32, out: [T][64] f32.
// Memory floor ~536 MB @ 6.3 TB/s => ~85 us; pure-FMA floor 8.6 GFLOP @157 TF => ~55 us.
//
// Round-3 structure (registers budgeted explicitly, no scalarization gamble):
//  - __launch_bounds__(256,4): 128-VGPR budget so the compiler KEEPS the tile
//    (rounds 1-2 it targeted 8 waves/SIMD and split my loops; VGPR=36/56).
//  - W transposed into LDS Wt[k][o], pad 68 words/row: per-(kc) chunk each
//    thread does 8 ds_read_b128, addresses spread across all 32 banks
//    (2-way max = free), 8-way t_sub-duplicate = broadcast.
//  - Thread tile: 8 tokens x 8 outputs = 64 loop-carried accumulators.
//    Wave = 8 t_sub x 8 o_sub covers 64 consecutive tokens, full rows.
//  - x read exactly once (8 dwordx4/kc, coalescer dedups 8-way duplicates);
//    stores: o_sub-fast lane order -> each wave store pair covers 2 KB
//    contiguous (kills round-1/2's ~2x write amplification).
//  - Grid-stride over 4096 token-batches with 1024 blocks (4/CU) so the
//    one-time W staging is amortized.

#define N_DIM   64
#define TOKENS  (1u << 20)          // 32 * 32768
#define NBATCH  (TOKENS / 256)      // token batches of 256 (one block-step)
#define WROW    68                  // padded LDS row stride (words)

__global__ __launch_bounds__(256, 4) void poslin_relu_kernel(
    const float* __restrict__ x,
    const float* __restrict__ W,
    const float* __restrict__ bias,
    float* __restrict__ out)
{
    __shared__ float Wt[N_DIM * WROW];  // Wt[k*WROW + o] = W[o][k], 17408 B

    const int tid = threadIdx.x;

    // ---- stage W transposed into LDS (once per block) ----
    {
        const int o  = tid >> 2;          // 0..63
        const int k0 = (tid & 3) << 4;    // 0,16,32,48
        const float4* wr = reinterpret_cast<const float4*>(W + o * N_DIM + k0);
#pragma unroll
        for (int q = 0; q < 4; ++q) {
            float4 v = wr[q];
            Wt[(k0 + 4 * q + 0) * WROW + o] = v.x;
            Wt[(k0 + 4 * q + 1) * WROW + o] = v.y;
            Wt[(k0 + 4 * q + 2) * WROW + o] = v.z;
            Wt[(k0 + 4 * q + 3) * WROW + o] = v.w;
        }
    }

    const int wv    = tid >> 6;        // wave id 0..3
    const int lane  = tid & 63;
    const int o_sub = lane & 7;        // output slice (fast across lanes)
    const int t_sub = (lane >> 3) & 7; // token subgroup
    const int obase = o_sub * 8;

    const float4 bz0 = *reinterpret_cast<const float4*>(bias + obase);
    const float4 bz1 = *reinterpret_cast<const float4*>(bias + obase + 4);

    __syncthreads();

#define FMA8(xc, wk0, wk1)                                                 \
    acc[j][0] = fmaf(xc, (wk0).x, acc[j][0]);                              \
    acc[j][1] = fmaf(xc, (wk0).y, acc[j][1]);                              \
    acc[j][2] = fmaf(xc, (wk0).z, acc[j][2]);                              \
    acc[j][3] = fmaf(xc, (wk0).w, acc[j][3]);                              \
    acc[j][4] = fmaf(xc, (wk1).x, acc[j][4]);                              \
    acc[j][5] = fmaf(xc, (wk1).y, acc[j][5]);                              \
    acc[j][6] = fmaf(xc, (wk1).z, acc[j][6]);                              \
    acc[j][7] = fmaf(xc, (wk1).w, acc[j][7]);

    for (unsigned tb = blockIdx.x; tb < NBATCH; tb += gridDim.x) {
        const size_t tk0  = (size_t)tb * 256 + (size_t)wv * 64 + t_sub; // token of j=0
        const float* xrow = x + tk0 * N_DIM;

        float acc[8][8];
#pragma unroll
        for (int j = 0; j < 8; ++j) {
            acc[j][0] = bz0.x; acc[j][1] = bz0.y; acc[j][2] = bz0.z; acc[j][3] = bz0.w;
            acc[j][4] = bz1.x; acc[j][5] = bz1.y; acc[j][6] = bz1.z; acc[j][7] = bz1.w;
        }

#pragma unroll 1
        for (int kc = 0; kc < 16; ++kc) {
            // W chunk: 4 k-values x 8 outputs = 8 x ds_read_b128
            float4 w0[4], w1[4];
#pragma unroll
            for (int k = 0; k < 4; ++k) {
                const float* wp = &Wt[(4 * kc + k) * WROW + obase];
                w0[k] = *reinterpret_cast<const float4*>(wp);
                w1[k] = *reinterpret_cast<const float4*>(wp + 4);
            }
#pragma unroll
            for (int j = 0; j < 8; ++j) {
                const float4 xv =
                    *reinterpret_cast<const float4*>(xrow + (size_t)j * 8 * N_DIM + 4 * kc);
                FMA8(xv.x, w0[0], w1[0]);
                FMA8(xv.y, w0[1], w1[1]);
                FMA8(xv.z, w0[2], w1[2]);
                FMA8(xv.w, w0[3], w1[3]);
            }
        }

        // ReLU + store: lane order (o_sub fast) -> wave covers 2 KB contiguous
#pragma unroll
        for (int j = 0; j < 8; ++j) {
            float4 r0, r1;
            r0.x = fmaxf(acc[j][0], 0.0f); r0.y = fmaxf(acc[j][1], 0.0f);
            r0.z = fmaxf(acc[j][2], 0.0f); r0.w = fmaxf(acc[j][3], 0.0f);
            r1.x = fmaxf(acc[j][4], 0.0f); r1.y = fmaxf(acc[j][5], 0.0f);
            r1.z = fmaxf(acc[j][6], 0.0f); r1.w = fmaxf(acc[j][7], 0.0f);
            float* op = out + (tk0 + (size_t)j * 8) * N_DIM + obase;
            *reinterpret_cast<float4*>(op)     = r0;
            *reinterpret_cast<float4*>(op + 4) = r1;
        }
    }
#undef FMA8
}

extern "C" void kernel_launch(void* const* d_in, const int* in_sizes, int n_in,
                              void* d_out, int out_size, void* d_ws, size_t ws_size,
                              hipStream_t stream) {
    const float* x    = (const float*)d_in[0];
    const float* W    = (const float*)d_in[1];
    const float* bias = (const float*)d_in[2];
    float* out        = (float*)d_out;

    const int block = 256;
    const int grid  = 1024;  // 4 blocks/CU; grid-stride over 4096 batches
    poslin_relu_kernel<<<grid, block, 0, stream>>>(x, W, bias, out);
}

// Round 4
// 153.515 us; speedup vs baseline: 2.5835x; 1.9544x over previous
//
#include <hip/hip_runtime.h>

// PositionLinear + ReLU: out[t,:] = relu(W @ x[t,:] + b)
// x: [1M][64] f32, W: [64][64] f32, b: [64], out: [1M][64] f32.
// HBM floor ~536 MB @ 6.3 TB/s => ~85 us. FMA floor 8.6 GFLOP @ 157 TF => ~55 us.
//
// Round 4: kill the 3.2x x-read amplification (round-3 FETCH=844 MB) by
// staging x through LDS with fully-coalesced global_load_lds (every line
// consumed 100% at fetch time), double-buffered so HBM latency hides under
// compute. XOR-swizzled source addresses (involution chunk^=(row&7)) give
// conflict-free ds_read_b128 on the compute side with a linear LDS dest
// (global_load_lds requires linear; swizzle lives in the per-lane global
// address — both-sides-or-neither rule).

#define NDIM    64
#define TOKENS  (1u << 20)
#define BTOK    128                  // tokens per batch per block
#define NBATCH  (TOKENS / BTOK)      // 8192
#define XBUF_F  (BTOK * NDIM)        // 8192 floats = 32 KB per buffer
#define GRIDX   512                  // 2 blocks/CU
#define NB_PER  (NBATCH / GRIDX)     // 16 batches per block

__device__ __forceinline__ void gload_lds16(const float* gsrc, float* ldst) {
    // dest = ldst + lane*16B (wave-uniform base); gsrc is per-lane.
    __builtin_amdgcn_global_load_lds(
        (const __attribute__((address_space(1))) void*)gsrc,
        (__attribute__((address_space(3))) void*)ldst,
        16, 0, 0);
}

__global__ __launch_bounds__(256, 2) void poslin_relu_kernel(
    const float* __restrict__ x,
    const float* __restrict__ W,
    const float* __restrict__ bias,
    float* __restrict__ out)
{
    __shared__ float Wt[NDIM * NDIM];   // Wt[k*64+o] = W[o][k]  (16 KB)
    __shared__ float xb[2 * XBUF_F];    // x double buffer       (64 KB)

    const int tid   = threadIdx.x;
    const int wv    = tid >> 6;         // wave 0..3
    const int lane  = tid & 63;
    const int o_sub = lane & 7;         // output slice (fast)
    const int t_sub = lane >> 3;        // token subgroup 0..7
    const int obase = o_sub * 8;

    // ---- stage W transposed into LDS (once) ----
    {
        const int o  = tid >> 2;
        const int k0 = (tid & 3) << 4;
        const float4* wr = reinterpret_cast<const float4*>(W + o * NDIM + k0);
#pragma unroll
        for (int q = 0; q < 4; ++q) {
            float4 v = wr[q];
            Wt[(k0 + 4 * q + 0) * NDIM + o] = v.x;
            Wt[(k0 + 4 * q + 1) * NDIM + o] = v.y;
            Wt[(k0 + 4 * q + 2) * NDIM + o] = v.z;
            Wt[(k0 + 4 * q + 3) * NDIM + o] = v.w;
        }
    }

    const float4 bz0 = *reinterpret_cast<const float4*>(bias + obase);
    const float4 bz1 = *reinterpret_cast<const float4*>(bias + obase + 4);

    // Staging: wave wv fills rows [wv*32, wv*32+32) = slots [wv*512, +512).
    // 8 x gload_lds(16B) per wave. LDS slot (r,s) <- global chunk (r, s^(r&7)).
    const int slot0 = wv * 512 + lane;
    auto stage = [&](unsigned bi, int bufidx) {
        const float* xsrc = x + (size_t)bi * (BTOK * NDIM);
#pragma unroll
        for (int q = 0; q < 8; ++q) {
            const int slot  = slot0 + q * 64;
            const int r     = slot >> 4;
            const int s     = slot & 15;
            const int chunk = (r << 4) + (s ^ (r & 7));
            gload_lds16(xsrc + 4 * chunk,
                        &xb[(size_t)bufidx * XBUF_F + (wv * 512 + q * 64) * 4]);
        }
    };

#define FMA_K(xc, a0v, a1v)                                                \
    acc[j][0] = fmaf(xc, (a0v).x, acc[j][0]);                              \
    acc[j][1] = fmaf(xc, (a0v).y, acc[j][1]);                              \
    acc[j][2] = fmaf(xc, (a0v).z, acc[j][2]);                              \
    acc[j][3] = fmaf(xc, (a0v).w, acc[j][3]);                              \
    acc[j][4] = fmaf(xc, (a1v).x, acc[j][4]);                              \
    acc[j][5] = fmaf(xc, (a1v).y, acc[j][5]);                              \
    acc[j][6] = fmaf(xc, (a1v).z, acc[j][6]);                              \
    acc[j][7] = fmaf(xc, (a1v).w, acc[j][7]);

    // Prologue: stage first batch, wait, barrier (also covers Wt staging).
    stage(blockIdx.x, 0);
    asm volatile("s_waitcnt vmcnt(0)" ::: "memory");
    __syncthreads();

    int cur = 0;
    for (unsigned m = 0; m < NB_PER; ++m) {
        const unsigned bi = blockIdx.x + m * GRIDX;

        if (m + 1 < NB_PER)
            stage(blockIdx.x + (m + 1) * GRIDX, cur ^ 1);  // hidden under compute

        const float* xs = &xb[(size_t)cur * XBUF_F];

        float acc[4][8];
#pragma unroll
        for (int j = 0; j < 4; ++j) {
            acc[j][0] = bz0.x; acc[j][1] = bz0.y; acc[j][2] = bz0.z; acc[j][3] = bz0.w;
            acc[j][4] = bz1.x; acc[j][5] = bz1.y; acc[j][6] = bz1.z; acc[j][7] = bz1.w;
        }

#pragma unroll 2
        for (int kc = 0; kc < 16; ++kc) {
            float4 w0[4], w1[4];
#pragma unroll
            for (int k = 0; k < 4; ++k) {
                const float* wp = &Wt[(kc * 4 + k) * NDIM + obase];
                w0[k] = *reinterpret_cast<const float4*>(wp);
                w1[k] = *reinterpret_cast<const float4*>(wp + 4);
            }
#pragma unroll
            for (int j = 0; j < 4; ++j) {
                const int r = wv * 32 + j * 8 + t_sub;      // r&7 == t_sub
                const float4 xv = *reinterpret_cast<const float4*>(
                    xs + r * NDIM + ((kc ^ t_sub) << 2));   // un-swizzle on read
                FMA_K(xv.x, w0[0], w1[0]);
                FMA_K(xv.y, w0[1], w1[1]);
                FMA_K(xv.z, w0[2], w1[2]);
                FMA_K(xv.w, w0[3], w1[3]);
            }
        }

        // ReLU + store: per instr, 8 consecutive rows x 8 o_sub slices ->
        // 2 KB contiguous per wave store pair, fully coalesced.
        const size_t t0 = (size_t)bi * BTOK;
#pragma unroll
        for (int j = 0; j < 4; ++j) {
            const int r = wv * 32 + j * 8 + t_sub;
            float4 r0, r1;
            r0.x = fmaxf(acc[j][0], 0.0f); r0.y = fmaxf(acc[j][1], 0.0f);
            r0.z = fmaxf(acc[j][2], 0.0f); r0.w = fmaxf(acc[j][3], 0.0f);
            r1.x = fmaxf(acc[j][4], 0.0f); r1.y = fmaxf(acc[j][5], 0.0f);
            r1.z = fmaxf(acc[j][6], 0.0f); r1.w = fmaxf(acc[j][7], 0.0f);
            float* op = out + (t0 + r) * NDIM + obase;
            *reinterpret_cast<float4*>(op)     = r0;
            *reinterpret_cast<float4*>(op + 4) = r1;
        }

        asm volatile("s_waitcnt vmcnt(0)" ::: "memory");
        __syncthreads();   // next buffer staged; cur buffer free to overwrite
        cur ^= 1;
    }
#undef FMA_K
}

extern "C" void kernel_launch(void* const* d_in, const int* in_sizes, int n_in,
                              void* d_out, int out_size, void* d_ws, size_t ws_size,
                              hipStream_t stream) {
    const float* x    = (const float*)d_in[0];
    const float* W    = (const float*)d_in[1];
    const float* bias = (const float*)d_in[2];
    float* out        = (float*)d_out;

    poslin_relu_kernel<<<GRIDX, 256, 0, stream>>>(x, W, bias, out);
}